// Round 5
// baseline (103.740 us; speedup 1.0000x reference)
//
#include <hip/hip_runtime.h>
#include <cstdint>

// B=16384 rows, K=2048 centers, D=128, T=1.0
// Outputs (flat, f32): out[B*D], center[K*D], label[B]
#define NB 16384
#define NK 2048
#define ND 128
#define MARGIN 0.10f
#define CAP 2048
#define XPITCH 132   // padded LDS x-row stride (floats): breaks bank aliasing

typedef __attribute__((ext_vector_type(8))) short bf16x8;
typedef __attribute__((ext_vector_type(4))) float f32x4;
typedef unsigned long long u64;

__device__ __forceinline__ unsigned short f2bf(float f) {
    unsigned u = __float_as_uint(f);
    u += 0x7fffu + ((u >> 16) & 1u);          // round-to-nearest-even
    return (unsigned short)(u >> 16);
}

// ---------------------------------------------------------------------------
// Prep (392 blocks):
//  [0,128)    cbf: center -> bf16 MFMA B-frag layout
//  [128,136)  c2 (chain identical to R1)
//  [136,392)  center passthrough copy (float4)
// ---------------------------------------------------------------------------
__global__ __launch_bounds__(256)
void prep(const float* __restrict__ c,
          unsigned short* __restrict__ cbf,
          float* __restrict__ c2,
          float* __restrict__ out_center) {
    const int bid = blockIdx.x;
    const int tid = threadIdx.x;
    if (bid < 128) {
        int t = bid * 256 + tid;              // 0..32767
        int lane = t & 63, s = (t >> 6) & 3, kt = t >> 8;
        int kc = kt * 16 + (lane & 15);
        int d0 = s * 32 + (lane >> 4) * 8;
        const float* src = c + (long)kc * ND + d0;
        unsigned short h[8];
#pragma unroll
        for (int j = 0; j < 8; ++j) h[j] = f2bf(src[j]);
        int4 pk;
        pk.x = h[0] | (h[1] << 16); pk.y = h[2] | (h[3] << 16);
        pk.z = h[4] | (h[5] << 16); pk.w = h[6] | (h[7] << 16);
        ((int4*)cbf)[t] = pk;
    } else if (bid < 136) {
        int k = (bid - 128) * 256 + tid;      // 0..2047
        const float4* row = (const float4*)(c + (long)k * ND);
        float s = 0.f;
#pragma unroll 8
        for (int i = 0; i < ND / 4; ++i) {
            float4 v = row[i];
            s += v.x * v.x + v.y * v.y + v.z * v.z + v.w * v.w;
        }
        c2[k] = s;
    } else {
        int i = (bid - 136) * 256 + tid;      // 0..K*D/4-1
        ((float4*)out_center)[i] = ((const float4*)c)[i];
    }
}

// ---------------------------------------------------------------------------
// Main: 256 blocks x 512 threads (8 waves). Block owns 64 rows x ALL 2048 k
// -> block min IS the global min. Wave w covers k in [w*256, w*256+256),
// computing 4 row-tiles (64 rows) per MFMA iteration.
//
// History:
//  R1: 32 rows, (256,2): 49 us, MfmaUtil 13% -- latency-bound.
//  R2: (1024,8): forced <=64 VGPR, spilled, 131 us.
//  R3: 32 rows, (512,4): ~38 us. 4 waves/SIMD.
//  R4: +1-deep prefetch, c2->LDS: NEUTRAL -> latency already TLP-covered;
//      the cost is the L2 stream volume + per-block fixed overhead.
//  R5: 64 rows/block (256 blocks): halves total cbf L2 traffic (512->256 MB)
//      and halves per-block fixed costs; MFMA total unchanged. A-frags for
//      4 row-tiles = 64 VGPR -> live set ~170 -> (512,2): 2 waves/SIMD at
//      the 256-VGPR bin, no spills (R2 lesson: never force a too-small bin).
// ---------------------------------------------------------------------------
__global__ __launch_bounds__(512, 2)
void kmeans_main(const float* __restrict__ x,
                 const float* __restrict__ center,
                 const unsigned short* __restrict__ cbf,
                 const float* __restrict__ c2,
                 float* __restrict__ out,
                 float* __restrict__ label_out) {
    __shared__ float xs[64 * XPITCH];         // 33.8 KB fp32 x rows
    __shared__ float c2s[NK];                 // 8 KB center norms
    __shared__ float x2s[64];
    __shared__ unsigned bmin[64];
    __shared__ u64 best[64];
    __shared__ unsigned buf[CAP];             // 8 KB candidate list
    __shared__ unsigned cnt;

    const int tid  = threadIdx.x;
    const int lane = tid & 63;
    const int wave = __builtin_amdgcn_readfirstlane(tid >> 6);  // 0..7
    const long rb  = (long)blockIdx.x * 64;

    // ---- stage x rows -> LDS (coalesced, 4 float4/thread) ----
#pragma unroll
    for (int t = tid; t < 64 * 32; t += 512) {
        int r = t >> 5, q = t & 31;
        ((float4*)(xs + r * XPITCH))[q] = ((const float4*)(x + (rb + r) * ND))[q];
    }
    // ---- stage c2 -> LDS (4 floats/thread, coalesced) ----
    ((float4*)c2s)[tid] = ((const float4*)c2)[tid];
    if (tid < 64) { bmin[tid] = 0x7f800000u; best[tid] = ~0ULL; }
    if (tid == 0) cnt = 0;
    __syncthreads();

    // ---- x2 per row: chain IDENTICAL to R1 (float2, 6-level butterfly) ----
    for (int i = 0; i < 8; ++i) {
        int r = wave * 8 + i;
        float2 v = *(const float2*)(xs + r * XPITCH + lane * 2);
        float s = v.x * v.x + v.y * v.y;
#pragma unroll
        for (int off = 32; off; off >>= 1) s += __shfl_xor(s, off, 64);
        if (lane == 0) x2s[r] = s;
    }
    __syncthreads();

    // ---- A-frags into registers (4 row-tiles, reused by both sweeps) ----
    bf16x8 af[4][4];
#pragma unroll
    for (int rt = 0; rt < 4; ++rt)
#pragma unroll
        for (int s = 0; s < 4; ++s) {
            const float* p = xs + (rt * 16 + (lane & 15)) * XPITCH
                               + s * 32 + (lane >> 4) * 8;
            float4 u0 = ((const float4*)p)[0];
            float4 u1 = ((const float4*)p)[1];
            bf16x8 a;
            a[0] = (short)f2bf(u0.x); a[1] = (short)f2bf(u0.y);
            a[2] = (short)f2bf(u0.z); a[3] = (short)f2bf(u0.w);
            a[4] = (short)f2bf(u1.x); a[5] = (short)f2bf(u1.y);
            a[6] = (short)f2bf(u1.z); a[7] = (short)f2bf(u1.w);
            af[rt][s] = a;
        }

    float x2p[4][4];
#pragma unroll
    for (int rt = 0; rt < 4; ++rt)
#pragma unroll
        for (int reg = 0; reg < 4; ++reg)
            x2p[rt][reg] = x2s[rt * 16 + (lane >> 4) * 4 + reg];

    const bf16x8* CF = (const bf16x8*)cbf;
    const int kt0 = (wave * 256) >> 4;

    // ---- sweep 1: min over this wave's 256 k, 64 rows ----
    float rmin[4][4];
#pragma unroll
    for (int rt = 0; rt < 4; ++rt)
#pragma unroll
        for (int reg = 0; reg < 4; ++reg) rmin[rt][reg] = __builtin_inff();

#pragma unroll 1
    for (int ct = 0; ct < 16; ++ct) {
        const int kt = kt0 + ct;
        bf16x8 bf[4];
#pragma unroll
        for (int s = 0; s < 4; ++s) bf[s] = CF[(kt * 4 + s) * 64 + lane];
        f32x4 acc[4];
#pragma unroll
        for (int rt = 0; rt < 4; ++rt) acc[rt] = (f32x4){0.f, 0.f, 0.f, 0.f};
#pragma unroll
        for (int s = 0; s < 4; ++s)
#pragma unroll
            for (int rt = 0; rt < 4; ++rt)
                acc[rt] = __builtin_amdgcn_mfma_f32_16x16x32_bf16(af[rt][s], bf[s], acc[rt], 0,0,0);
        float c2v = c2s[kt * 16 + (lane & 15)];
#pragma unroll
        for (int rt = 0; rt < 4; ++rt)
#pragma unroll
            for (int reg = 0; reg < 4; ++reg)
                rmin[rt][reg] = fminf(rmin[rt][reg],
                                      fmaf(-2.f, acc[rt][reg], x2p[rt][reg] + c2v));
    }

    // cross-lane min over the 16 cols (lane&15 group), then block combine
#pragma unroll
    for (int rt = 0; rt < 4; ++rt)
#pragma unroll
        for (int reg = 0; reg < 4; ++reg) {
            float v = rmin[rt][reg];
#pragma unroll
            for (int off = 1; off < 16; off <<= 1)
                v = fminf(v, __shfl_xor(v, off, 64));
            if ((lane & 15) == 0)             // d2a >= 0 -> uint order == float order
                atomicMin(&bmin[rt * 16 + (lane >> 4) * 4 + reg], __float_as_uint(v));
        }
    __syncthreads();

    float thr[4][4];
#pragma unroll
    for (int rt = 0; rt < 4; ++rt)
#pragma unroll
        for (int reg = 0; reg < 4; ++reg)
            thr[rt][reg] = __uint_as_float(bmin[rt * 16 + (lane >> 4) * 4 + reg]) + MARGIN;

    // ---- sweep 2: recompute, filter candidates within MARGIN of block min ----
#pragma unroll 1
    for (int ct = 0; ct < 16; ++ct) {
        const int kt = kt0 + ct;
        bf16x8 bf[4];
#pragma unroll
        for (int s = 0; s < 4; ++s) bf[s] = CF[(kt * 4 + s) * 64 + lane];
        f32x4 acc[4];
#pragma unroll
        for (int rt = 0; rt < 4; ++rt) acc[rt] = (f32x4){0.f, 0.f, 0.f, 0.f};
#pragma unroll
        for (int s = 0; s < 4; ++s)
#pragma unroll
            for (int rt = 0; rt < 4; ++rt)
                acc[rt] = __builtin_amdgcn_mfma_f32_16x16x32_bf16(af[rt][s], bf[s], acc[rt], 0,0,0);
        float c2v = c2s[kt * 16 + (lane & 15)];
        const int col = kt * 16 + (lane & 15);
#pragma unroll
        for (int rt = 0; rt < 4; ++rt)
#pragma unroll
            for (int reg = 0; reg < 4; ++reg) {
                float d2a = fmaf(-2.f, acc[rt][reg], x2p[rt][reg] + c2v);
                if (d2a <= thr[rt][reg]) {
                    unsigned rloc = rt * 16 + (lane >> 4) * 4 + reg;   // 0..63
                    unsigned idx = atomicAdd(&cnt, 1u);
                    if (idx < CAP) buf[idx] = (rloc << 11) | (unsigned)col;
                }
            }
    }
    __syncthreads();

    // ---- exact refine: fp32 chain IDENTICAL to R1 (serial fmaf dot,
    //      t=x2+c2, fmaf(-2,dot,t), max, sqrt; u64 key -> lowest k on tie) ----
    unsigned n = cnt; if (n > CAP) n = CAP;
    for (unsigned i = tid; i < n; i += 512) {
        unsigned pc = buf[i];
        int rloc = pc >> 11, col = pc & (NK - 1);
        const float* xr = xs + rloc * XPITCH;
        const float* cr = center + (long)col * ND;
        float dot = 0.f;
#pragma unroll 8
        for (int d = 0; d < ND; ++d) dot = fmaf(xr[d], cr[d], dot);
        float t = x2s[rloc] + c2s[col];
        float f = fmaxf(fmaf(-2.0f, dot, t), 0.0f);
        float s = __builtin_sqrtf(f);
        u64 key = ((u64)__float_as_uint(s) << 32) | (unsigned)col;
        atomicMin(&best[rloc], key);
    }
    __syncthreads();

    // ---- direct output: gather center[bk] per row + label ----
    for (int i = 0; i < 8; ++i) {
        int rloc = wave * 8 + i;
        int bk = (int)(best[rloc] & 0xffffffffULL);
        float2 cv = ((const float2*)(center + (long)bk * ND))[lane];
        ((float2*)(out + (rb + rloc) * ND))[lane] = cv;
        if (lane == 0) label_out[rb + rloc] = (float)bk;
    }
}

// ---------------------------------------------------------------------------
extern "C" void kernel_launch(void* const* d_in, const int* in_sizes, int n_in,
                              void* d_out, int out_size, void* d_ws, size_t ws_size,
                              hipStream_t stream) {
    const float* x      = (const float*)d_in[0];   // [B][D]
    const float* center = (const float*)d_in[1];   // [K][D]
    float* out = (float*)d_out;

    float* out_x      = out;                        // [B*D]
    float* out_center = out + (long)NB * ND;        // [K*D]
    float* out_label  = out_center + (long)NK * ND; // [B]

    // Workspace: cbf[K*D]u16 (0.5MB), c2[K]f32
    unsigned short* cbf = (unsigned short*)d_ws;
    float* c2 = (float*)(cbf + (size_t)NK * ND);

    prep<<<392, 256, 0, stream>>>(center, cbf, c2, out_center);
    kmeans_main<<<NB / 64, 512, 0, stream>>>(x, center, cbf, c2,
                                             out_x, out_label);
}